// Round 1
// baseline (468.329 us; speedup 1.0000x reference)
//
#include <hip/hip_runtime.h>
#include <hip/hip_fp16.h>

// Problem dims
#define B_ 2
#define S_ 2048
#define E_ 768
#define H_ 12
#define D_ 64
#define BS_ 4096   // B_*S_

typedef _Float16 half8 __attribute__((ext_vector_type(8)));
typedef _Float16 half4 __attribute__((ext_vector_type(4)));
typedef float f32x4 __attribute__((ext_vector_type(4)));

__device__ __forceinline__ f32x4 mfma16(half8 a, half8 b, f32x4 c) {
    return __builtin_amdgcn_mfma_f32_16x16x32_f16(a, b, c, 0, 0, 0);
}

// ---------------- cast x (f32 -> f16) ----------------
__global__ void cast_x_kernel(const float* __restrict__ x, _Float16* __restrict__ xh, int n) {
    int i = (blockIdx.x * blockDim.x + threadIdx.x) * 4;
    if (i < n) {
        float4 v = *reinterpret_cast<const float4*>(x + i);
        half4 o;
        o.x = (_Float16)v.x; o.y = (_Float16)v.y; o.z = (_Float16)v.z; o.w = (_Float16)v.w;
        *reinterpret_cast<half4*>(xh + i) = o;
    }
}

// ---------------- transpose W (f32 [in][out] -> f16 [out][in]) ----------------
__global__ void transpose_w_kernel(const float* __restrict__ W0, const float* __restrict__ W1,
                                   const float* __restrict__ W2, const float* __restrict__ W3,
                                   _Float16* __restrict__ Wt) {
    __shared__ float tile[32][33];
    int mat = blockIdx.z;
    const float* W = (mat == 0) ? W0 : (mat == 1) ? W1 : (mat == 2) ? W2 : W3;
    _Float16* dst = Wt + (size_t)mat * E_ * E_;
    int out0 = blockIdx.x * 32, in0 = blockIdx.y * 32;
    int tx = threadIdx.x & 31, ty = threadIdx.x >> 5;  // 32 x 8
    #pragma unroll
    for (int r = ty; r < 32; r += 8) tile[r][tx] = W[(size_t)(in0 + r) * E_ + out0 + tx];
    __syncthreads();
    #pragma unroll
    for (int r = ty; r < 32; r += 8) dst[(size_t)(out0 + r) * E_ + in0 + tx] = (_Float16)tile[tx][r];
}

// ---------------- fused QKV GEMM ----------------
// y = x @ W + b ; W pre-transposed to [out][in]. Writes q,k as [B,H,S,D], v as [B,H,D,S].
__global__ __launch_bounds__(256) void qkv_kernel(const _Float16* __restrict__ xh,
                                                  const _Float16* __restrict__ Wt,
                                                  const float* __restrict__ bq, const float* __restrict__ bk,
                                                  const float* __restrict__ bv,
                                                  _Float16* __restrict__ qw, _Float16* __restrict__ kw,
                                                  _Float16* __restrict__ vT) {
    int n0 = blockIdx.x * 64;              // 0..2304 (3 matrices concatenated)
    int m0 = blockIdx.y * 64;
    int mat = n0 / E_;
    int col0 = n0 - mat * E_;
    int lane = threadIdx.x & 63, w = threadIdx.x >> 6;
    int l15 = lane & 15, lhi = lane >> 4;
    const _Float16* Wm = Wt + (size_t)mat * E_ * E_;
    int arow = m0 + 16 * w + l15;
    const _Float16* aptr = xh + (size_t)arow * E_ + lhi * 8;

    f32x4 acc[4];
    #pragma unroll
    for (int j = 0; j < 4; ++j) acc[j] = (f32x4){0.f, 0.f, 0.f, 0.f};

    for (int kk = 0; kk < E_; kk += 32) {
        half8 a = *reinterpret_cast<const half8*>(aptr + kk);
        #pragma unroll
        for (int j = 0; j < 4; ++j) {
            half8 b = *reinterpret_cast<const half8*>(Wm + (size_t)(col0 + 16 * j + l15) * E_ + kk + lhi * 8);
            acc[j] = mfma16(a, b, acc[j]);
        }
    }

    const float* bias = (mat == 0) ? bq : (mat == 1) ? bk : bv;
    #pragma unroll
    for (int j = 0; j < 4; ++j) {
        int col = col0 + 16 * j + l15;   // column within this matrix (0..767)
        int h = col >> 6, d = col & 63;
        float bsv = bias[col];
        #pragma unroll
        for (int r = 0; r < 4; ++r) {
            int token = m0 + 16 * w + lhi * 4 + r;
            int bb = token >> 11, s = token & (S_ - 1);
            _Float16 val = (_Float16)(acc[j][r] + bsv);
            if (mat == 0)      qw[(((size_t)bb * H_ + h) * S_ + s) * D_ + d] = val;
            else if (mat == 1) kw[(((size_t)bb * H_ + h) * S_ + s) * D_ + d] = val;
            else               vT[(((size_t)bb * H_ + h) * D_ + d) * S_ + s] = val;
        }
    }
}

// ---------------- attention: scores + softmax weights + PV ----------------
// grid: (S/64, H, B); 4 waves; each wave owns 16 queries.
__global__ __launch_bounds__(256) void attn_kernel(const _Float16* __restrict__ qw,
                                                   const _Float16* __restrict__ kw,
                                                   const _Float16* __restrict__ vT,
                                                   float* __restrict__ wout,      // (B,H,S,S) f32
                                                   _Float16* __restrict__ aout) { // (B*S, E) f16
    __shared__ _Float16 plds[4][16][32];
    int qt = blockIdx.x, h = blockIdx.y, bb = blockIdx.z;
    int lane = threadIdx.x & 63, w = threadIdx.x >> 6;
    int l15 = lane & 15, lhi = lane >> 4;
    int q0 = qt * 64 + 16 * w;
    size_t bh = (size_t)bb * H_ + h;
    const _Float16* qbase = qw + bh * S_ * D_;
    const _Float16* kbase = kw + bh * S_ * D_;
    const _Float16* vbase = vT + bh * D_ * S_;

    // Q fragments for this wave's 16 queries (K=64 -> 2 k-fragments)
    half8 qa[2];
    #pragma unroll
    for (int kf = 0; kf < 2; ++kf)
        qa[kf] = *reinterpret_cast<const half8*>(qbase + (size_t)(q0 + l15) * D_ + kf * 32 + lhi * 8);

    // ---- pass 1: row sums of exp(s/8) ----
    float lsum[4] = {0.f, 0.f, 0.f, 0.f};
    for (int kt = 0; kt < S_ / 32; ++kt) {
        #pragma unroll
        for (int nf = 0; nf < 2; ++nf) {
            f32x4 sacc = (f32x4){0.f, 0.f, 0.f, 0.f};
            #pragma unroll
            for (int kf = 0; kf < 2; ++kf) {
                half8 kb = *reinterpret_cast<const half8*>(kbase + (size_t)(kt * 32 + nf * 16 + l15) * D_ + kf * 32 + lhi * 8);
                sacc = mfma16(qa[kf], kb, sacc);
            }
            #pragma unroll
            for (int r = 0; r < 4; ++r) lsum[r] += __expf(sacc[r] * 0.125f);
        }
    }
    #pragma unroll
    for (int r = 0; r < 4; ++r) {
        float v = lsum[r];
        v += __shfl_xor(v, 1);
        v += __shfl_xor(v, 2);
        v += __shfl_xor(v, 4);
        v += __shfl_xor(v, 8);
        lsum[r] = 1.0f / v;   // reciprocal row-sum, shared by the 16-lane group
    }

    // ---- pass 2: recompute scores (bitwise identical), write weights, accumulate PV ----
    f32x4 oacc[4];
    #pragma unroll
    for (int df = 0; df < 4; ++df) oacc[df] = (f32x4){0.f, 0.f, 0.f, 0.f};
    float* wbase = wout + bh * (size_t)S_ * S_;

    for (int kt = 0; kt < S_ / 32; ++kt) {
        #pragma unroll
        for (int nf = 0; nf < 2; ++nf) {
            f32x4 sacc = (f32x4){0.f, 0.f, 0.f, 0.f};
            #pragma unroll
            for (int kf = 0; kf < 2; ++kf) {
                half8 kb = *reinterpret_cast<const half8*>(kbase + (size_t)(kt * 32 + nf * 16 + l15) * D_ + kf * 32 + lhi * 8);
                sacc = mfma16(qa[kf], kb, sacc);
            }
            #pragma unroll
            for (int r = 0; r < 4; ++r) {
                float p = __expf(sacc[r] * 0.125f) * lsum[r];
                wbase[(size_t)(q0 + lhi * 4 + r) * S_ + kt * 32 + nf * 16 + l15] = p;
                plds[w][lhi * 4 + r][nf * 16 + l15] = (_Float16)p;
            }
        }
        // A fragment for PV: p[16q x 32k], contiguous-8 along k from per-wave LDS
        half8 pa = *reinterpret_cast<const half8*>(&plds[w][l15][lhi * 8]);
        #pragma unroll
        for (int df = 0; df < 4; ++df) {
            half8 vb = *reinterpret_cast<const half8*>(vbase + (size_t)(df * 16 + l15) * S_ + kt * 32 + lhi * 8);
            oacc[df] = mfma16(pa, vb, oacc[df]);
        }
    }

    // write attention output as [token][E] f16 for the out-projection GEMM
    #pragma unroll
    for (int df = 0; df < 4; ++df) {
        #pragma unroll
        for (int r = 0; r < 4; ++r) {
            int token = bb * S_ + q0 + lhi * 4 + r;
            aout[(size_t)token * E_ + h * D_ + df * 16 + l15] = (_Float16)(oacc[df][r]);
        }
    }
}

// ---------------- output projection GEMM ----------------
__global__ __launch_bounds__(256) void proj_kernel(const _Float16* __restrict__ ah,
                                                   const _Float16* __restrict__ Wto,
                                                   const float* __restrict__ bo,
                                                   float* __restrict__ out) {
    int n0 = blockIdx.x * 64;
    int m0 = blockIdx.y * 64;
    int lane = threadIdx.x & 63, w = threadIdx.x >> 6;
    int l15 = lane & 15, lhi = lane >> 4;
    const _Float16* aptr = ah + (size_t)(m0 + 16 * w + l15) * E_ + lhi * 8;

    f32x4 acc[4];
    #pragma unroll
    for (int j = 0; j < 4; ++j) acc[j] = (f32x4){0.f, 0.f, 0.f, 0.f};

    for (int kk = 0; kk < E_; kk += 32) {
        half8 a = *reinterpret_cast<const half8*>(aptr + kk);
        #pragma unroll
        for (int j = 0; j < 4; ++j) {
            half8 b = *reinterpret_cast<const half8*>(Wto + (size_t)(n0 + 16 * j + l15) * E_ + kk + lhi * 8);
            acc[j] = mfma16(a, b, acc[j]);
        }
    }
    #pragma unroll
    for (int j = 0; j < 4; ++j) {
        int col = n0 + 16 * j + l15;
        float bsv = bo[col];
        #pragma unroll
        for (int r = 0; r < 4; ++r) {
            int token = m0 + 16 * w + lhi * 4 + r;
            out[(size_t)token * E_ + col] = acc[j][r] + bsv;
        }
    }
}

extern "C" void kernel_launch(void* const* d_in, const int* in_sizes, int n_in,
                              void* d_out, int out_size, void* d_ws, size_t ws_size,
                              hipStream_t stream) {
    const float* x  = (const float*)d_in[0];
    const float* Wq = (const float*)d_in[1];
    const float* bq = (const float*)d_in[2];
    const float* Wk = (const float*)d_in[3];
    const float* bk = (const float*)d_in[4];
    const float* Wv = (const float*)d_in[5];
    const float* bv = (const float*)d_in[6];
    const float* Wo = (const float*)d_in[7];
    const float* bo = (const float*)d_in[8];

    char* ws = (char*)d_ws;
    // ws layout (bytes): all f16
    _Float16* xh   = (_Float16*)(ws);                 // 4096*768           = 6,291,456 B
    _Float16* Wt   = (_Float16*)(ws + 6291456);       // 4*768*768          = 4,718,592 B
    _Float16* qw   = (_Float16*)(ws + 11010048);      // [B,H,S,D]          = 6,291,456 B
    _Float16* kw   = (_Float16*)(ws + 17301504);      // [B,H,S,D]          = 6,291,456 B
    _Float16* vT   = (_Float16*)(ws + 23592960);      // [B,H,D,S]          = 6,291,456 B
    _Float16* aout = (_Float16*)(ws + 29884416);      // [B*S,E]            = 6,291,456 B
    (void)ws_size; (void)in_sizes; (void)n_in; (void)out_size;

    float* out  = (float*)d_out;                       // (B,S,E) f32
    float* wout = out + (size_t)BS_ * E_;              // (B,H,S,S) f32

    cast_x_kernel<<<dim3(BS_ * E_ / 1024), dim3(256), 0, stream>>>(x, xh, BS_ * E_);
    transpose_w_kernel<<<dim3(E_ / 32, E_ / 32, 4), dim3(256), 0, stream>>>(Wq, Wk, Wv, Wo, Wt);
    qkv_kernel<<<dim3(3 * E_ / 64, BS_ / 64), dim3(256), 0, stream>>>(xh, Wt, bq, bk, bv, qw, kw, vT);
    attn_kernel<<<dim3(S_ / 64, H_, B_), dim3(256), 0, stream>>>(qw, kw, vT, wout, aout);
    proj_kernel<<<dim3(E_ / 64, BS_ / 64), dim3(256), 0, stream>>>(aout, Wt + (size_t)3 * E_ * E_, bo, out);
}

// Round 2
// 235.826 us; speedup vs baseline: 1.9859x; 1.9859x over previous
//
#include <hip/hip_runtime.h>
#include <hip/hip_fp16.h>

// Problem dims
#define B_ 2
#define S_ 2048
#define E_ 768
#define H_ 12
#define D_ 64
#define BS_ 4096   // B_*S_

typedef _Float16 half8 __attribute__((ext_vector_type(8)));
typedef _Float16 half4 __attribute__((ext_vector_type(4)));
typedef float f32x4 __attribute__((ext_vector_type(4)));

__device__ __forceinline__ f32x4 mfma16(half8 a, half8 b, f32x4 c) {
    return __builtin_amdgcn_mfma_f32_16x16x32_f16(a, b, c, 0, 0, 0);
}

// async global->LDS, 16B per lane; LDS dst must be wave-uniform base (HW adds lane*16)
__device__ __forceinline__ void gll16(const void* g, void* s) {
    __builtin_amdgcn_global_load_lds((const __attribute__((address_space(1))) void*)g,
                                     (__attribute__((address_space(3))) void*)s, 16, 0, 0);
}

// ---------------- cast x (f32 -> f16) ----------------
__global__ void cast_x_kernel(const float* __restrict__ x, _Float16* __restrict__ xh, int n) {
    int i = (blockIdx.x * blockDim.x + threadIdx.x) * 4;
    if (i < n) {
        float4 v = *reinterpret_cast<const float4*>(x + i);
        half4 o;
        o.x = (_Float16)v.x; o.y = (_Float16)v.y; o.z = (_Float16)v.z; o.w = (_Float16)v.w;
        *reinterpret_cast<half4*>(xh + i) = o;
    }
}

// ---------------- transpose W (f32 [in][out] -> f16 [out][in]) ----------------
__global__ void transpose_w_kernel(const float* __restrict__ W0, const float* __restrict__ W1,
                                   const float* __restrict__ W2, const float* __restrict__ W3,
                                   _Float16* __restrict__ Wt) {
    __shared__ float tile[32][33];
    int mat = blockIdx.z;
    const float* W = (mat == 0) ? W0 : (mat == 1) ? W1 : (mat == 2) ? W2 : W3;
    _Float16* dst = Wt + (size_t)mat * E_ * E_;
    int out0 = blockIdx.x * 32, in0 = blockIdx.y * 32;
    int tx = threadIdx.x & 31, ty = threadIdx.x >> 5;  // 32 x 8
    #pragma unroll
    for (int r = ty; r < 32; r += 8) tile[r][tx] = W[(size_t)(in0 + r) * E_ + out0 + tx];
    __syncthreads();
    #pragma unroll
    for (int r = ty; r < 32; r += 8) dst[(size_t)(out0 + r) * E_ + in0 + tx] = (_Float16)tile[tx][r];
}

// ================= fused QKV GEMM (LDS double-buffered) =================
// Block tile 128(M) x 64(N), BK=32. 4 waves in 2x2; wave tile 64x32.
// A = xh [M][768] f16, B = Wt [N][768] f16 (pre-transposed). Swizzle c16 ^= (row>>1)&3.
__global__ __launch_bounds__(256) void qkv_kernel(const _Float16* __restrict__ xh,
                                                  const _Float16* __restrict__ Wt,
                                                  const float* __restrict__ bq, const float* __restrict__ bk,
                                                  const float* __restrict__ bv,
                                                  _Float16* __restrict__ qw, _Float16* __restrict__ kw,
                                                  _Float16* __restrict__ vT) {
    __shared__ __align__(16) _Float16 ldsA[2][128 * 32];
    __shared__ __align__(16) _Float16 ldsB[2][64 * 32];
    int n0 = blockIdx.x * 64;
    int m0 = blockIdx.y * 128;
    int mat = n0 / E_;
    int col0 = n0 - mat * E_;
    int tid = threadIdx.x;
    int lane = tid & 63, wv = tid >> 6;
    int l15 = lane & 15, lhi = lane >> 4;
    int wm = wv >> 1, wn = wv & 1;
    const _Float16* Wm = Wt + (size_t)mat * E_ * E_ + (size_t)col0 * E_;
    const _Float16* Am = xh + (size_t)m0 * E_;

    // staging lane geometry (rows of 64B = 4 chunks of 16B)
    int srowA = wv * 16 + (lane >> 2);   // + issue*64
    int sc16  = lane & 3;

    auto stage = [&](int buf, int k0) {
        // A: 128 rows x 64B, 2 issues
        #pragma unroll
        for (int is = 0; is < 2; ++is) {
            int row = is * 64 + srowA;
            const char* src = (const char*)(Am + (size_t)row * E_ + k0) + ((sc16 ^ ((row >> 1) & 3)) << 4);
            gll16(src, &ldsA[buf][is * 2048 + wv * 512]);
        }
        // B: 64 rows x 64B, 1 issue
        {
            int row = srowA;
            const char* src = (const char*)(Wm + (size_t)row * E_ + k0) + ((sc16 ^ ((row >> 1) & 3)) << 4);
            gll16(src, &ldsB[buf][wv * 512]);
        }
    };

    f32x4 acc[4][2];
    #pragma unroll
    for (int mi = 0; mi < 4; ++mi)
        #pragma unroll
        for (int nj = 0; nj < 2; ++nj) acc[mi][nj] = (f32x4){0.f, 0.f, 0.f, 0.f};

    stage(0, 0);
    __syncthreads();
    for (int t = 0; t < E_ / 32; ++t) {
        if (t + 1 < E_ / 32) stage((t + 1) & 1, (t + 1) * 32);
        const _Float16* At = ldsA[t & 1];
        const _Float16* Bt = ldsB[t & 1];
        half8 af[4], bf[2];
        #pragma unroll
        for (int mi = 0; mi < 4; ++mi) {
            int row = wm * 64 + mi * 16 + l15;
            af[mi] = *reinterpret_cast<const half8*>(At + row * 32 + ((lhi ^ ((row >> 1) & 3)) << 3));
        }
        #pragma unroll
        for (int nj = 0; nj < 2; ++nj) {
            int row = wn * 32 + nj * 16 + l15;
            bf[nj] = *reinterpret_cast<const half8*>(Bt + row * 32 + ((lhi ^ ((row >> 1) & 3)) << 3));
        }
        #pragma unroll
        for (int mi = 0; mi < 4; ++mi)
            #pragma unroll
            for (int nj = 0; nj < 2; ++nj) acc[mi][nj] = mfma16(af[mi], bf[nj], acc[mi][nj]);
        __syncthreads();
    }

    const float* bias = (mat == 0) ? bq : (mat == 1) ? bk : bv;
    #pragma unroll
    for (int nj = 0; nj < 2; ++nj) {
        int col = col0 + wn * 32 + nj * 16 + l15;   // column within this matrix (0..767)
        int h = col >> 6, d = col & 63;
        float bsv = bias[col];
        #pragma unroll
        for (int mi = 0; mi < 4; ++mi) {
            #pragma unroll
            for (int r = 0; r < 4; ++r) {
                int token = m0 + wm * 64 + mi * 16 + lhi * 4 + r;
                int bb = token >> 11, s = token & (S_ - 1);
                _Float16 val = (_Float16)(acc[mi][nj][r] + bsv);
                if (mat == 0)      qw[(((size_t)bb * H_ + h) * S_ + s) * D_ + d] = val;
                else if (mat == 1) kw[(((size_t)bb * H_ + h) * S_ + s) * D_ + d] = val;
                else               vT[(((size_t)bb * H_ + h) * D_ + d) * S_ + s] = val;
            }
        }
    }
}

// ================= attention (LDS-staged K/V, 2-pass, nontemporal weight stores) =================
// grid: (S/64, H, B); 4 waves; each wave owns 16 queries. 64-key steps.
__global__ __launch_bounds__(256) void attn_kernel(const _Float16* __restrict__ qw,
                                                   const _Float16* __restrict__ kw,
                                                   const _Float16* __restrict__ vT,
                                                   float* __restrict__ wout,      // (B,H,S,S) f32
                                                   _Float16* __restrict__ aout) { // (B*S, E) f16
    __shared__ __align__(16) _Float16 ldsK[2][64 * 64];
    __shared__ __align__(16) _Float16 ldsV[2][64 * 64];
    __shared__ __align__(16) _Float16 plds[4][16 * 64];
    int qt = blockIdx.x, h = blockIdx.y, bb = blockIdx.z;
    int tid = threadIdx.x;
    int lane = tid & 63, w = tid >> 6;
    int l15 = lane & 15, lhi = lane >> 4;
    int q0 = qt * 64 + 16 * w;
    size_t bh = (size_t)bb * H_ + h;
    const _Float16* qbase = qw + bh * S_ * D_;
    const _Float16* kbase = kw + bh * S_ * D_;
    const _Float16* vbase = vT + bh * D_ * S_;

    // staging lane geometry: tile rows of 128B = 8 chunks of 16B; 32 rows per issue
    int srow = w * 8 + (lane >> 3);  // + issue*32
    int sc16 = lane & 7;

    auto stageK = [&](int buf, int kt0) {
        #pragma unroll
        for (int is = 0; is < 2; ++is) {
            int row = is * 32 + srow;
            const char* src = (const char*)(kbase + (size_t)(kt0 + row) * D_) + ((sc16 ^ (row & 7)) << 4);
            gll16(src, &ldsK[buf][is * 2048 + w * 512]);
        }
    };
    auto stageV = [&](int buf, int kt0) {
        #pragma unroll
        for (int is = 0; is < 2; ++is) {
            int row = is * 32 + srow;  // row = d index
            const char* src = (const char*)(vbase + (size_t)row * S_ + kt0) + ((sc16 ^ (row & 7)) << 4);
            gll16(src, &ldsV[buf][is * 2048 + w * 512]);
        }
    };

    // Q fragments for this wave's 16 queries (K=64 -> 2 k-fragments)
    half8 qa[2];
    #pragma unroll
    for (int kf = 0; kf < 2; ++kf)
        qa[kf] = *reinterpret_cast<const half8*>(qbase + (size_t)(q0 + l15) * D_ + kf * 32 + lhi * 8);

    // ---- pass 1: row sums of exp(s/8) ----
    float lsum[4] = {0.f, 0.f, 0.f, 0.f};
    stageK(0, 0);
    __syncthreads();
    for (int kt = 0; kt < S_ / 64; ++kt) {
        if (kt + 1 < S_ / 64) stageK((kt + 1) & 1, (kt + 1) * 64);
        const _Float16* Kb = ldsK[kt & 1];
        #pragma unroll
        for (int nf = 0; nf < 4; ++nf) {
            f32x4 sacc = (f32x4){0.f, 0.f, 0.f, 0.f};
            int row = nf * 16 + l15;
            #pragma unroll
            for (int kf = 0; kf < 2; ++kf) {
                half8 kb = *reinterpret_cast<const half8*>(Kb + row * 64 + (((kf * 4 + lhi) ^ (row & 7)) << 3));
                sacc = mfma16(qa[kf], kb, sacc);
            }
            #pragma unroll
            for (int r = 0; r < 4; ++r) lsum[r] += __expf(sacc[r] * 0.125f);
        }
        __syncthreads();
    }
    #pragma unroll
    for (int r = 0; r < 4; ++r) {
        float v = lsum[r];
        v += __shfl_xor(v, 1);
        v += __shfl_xor(v, 2);
        v += __shfl_xor(v, 4);
        v += __shfl_xor(v, 8);
        lsum[r] = 1.0f / v;   // reciprocal row-sum, shared by the 16-lane group
    }

    // ---- pass 2: recompute scores, write weights (nontemporal), accumulate PV ----
    f32x4 oacc[4];
    #pragma unroll
    for (int df = 0; df < 4; ++df) oacc[df] = (f32x4){0.f, 0.f, 0.f, 0.f};
    float* wbase = wout + bh * (size_t)S_ * S_;

    stageK(0, 0);
    stageV(0, 0);
    __syncthreads();
    for (int kt = 0; kt < S_ / 64; ++kt) {
        if (kt + 1 < S_ / 64) { stageK((kt + 1) & 1, (kt + 1) * 64); stageV((kt + 1) & 1, (kt + 1) * 64); }
        const _Float16* Kb = ldsK[kt & 1];
        const _Float16* Vb = ldsV[kt & 1];
        #pragma unroll
        for (int nf = 0; nf < 4; ++nf) {
            f32x4 sacc = (f32x4){0.f, 0.f, 0.f, 0.f};
            int row = nf * 16 + l15;
            #pragma unroll
            for (int kf = 0; kf < 2; ++kf) {
                half8 kb = *reinterpret_cast<const half8*>(Kb + row * 64 + (((kf * 4 + lhi) ^ (row & 7)) << 3));
                sacc = mfma16(qa[kf], kb, sacc);
            }
            #pragma unroll
            for (int r = 0; r < 4; ++r) {
                float p = __expf(sacc[r] * 0.125f) * lsum[r];
                int q = lhi * 4 + r;
                int k = nf * 16 + l15;
                __builtin_nontemporal_store(p, &wbase[(size_t)(q0 + q) * S_ + kt * 64 + k]);
                plds[w][q * 64 + (((k >> 3) ^ (q & 7)) << 3) + (k & 7)] = (_Float16)p;
            }
        }
        // PV: 2 k-sub-fragments of 32 keys each
        #pragma unroll
        for (int ks = 0; ks < 2; ++ks) {
            half8 pa = *reinterpret_cast<const half8*>(&plds[w][l15 * 64 + (((ks * 4 + lhi) ^ (l15 & 7)) << 3)]);
            #pragma unroll
            for (int df = 0; df < 4; ++df) {
                int drow = df * 16 + l15;
                half8 vb = *reinterpret_cast<const half8*>(Vb + drow * 64 + (((ks * 4 + lhi) ^ (drow & 7)) << 3));
                oacc[df] = mfma16(pa, vb, oacc[df]);
            }
        }
        __syncthreads();
    }

    // write attention output as [token][E] f16 for the out-projection GEMM
    #pragma unroll
    for (int df = 0; df < 4; ++df) {
        #pragma unroll
        for (int r = 0; r < 4; ++r) {
            int token = bb * S_ + q0 + lhi * 4 + r;
            aout[(size_t)token * E_ + h * D_ + df * 16 + l15] = (_Float16)(oacc[df][r]);
        }
    }
}

// ================= output projection GEMM (LDS double-buffered) =================
// Block tile 128 x 64, BK=32, same structure as qkv.
__global__ __launch_bounds__(256) void proj_kernel(const _Float16* __restrict__ ah,
                                                   const _Float16* __restrict__ Wto,
                                                   const float* __restrict__ bo,
                                                   float* __restrict__ out) {
    __shared__ __align__(16) _Float16 ldsA[2][128 * 32];
    __shared__ __align__(16) _Float16 ldsB[2][64 * 32];
    int n0 = blockIdx.x * 64;
    int m0 = blockIdx.y * 128;
    int tid = threadIdx.x;
    int lane = tid & 63, wv = tid >> 6;
    int l15 = lane & 15, lhi = lane >> 4;
    int wm = wv >> 1, wn = wv & 1;
    const _Float16* Am = ah + (size_t)m0 * E_;
    const _Float16* Bm = Wto + (size_t)n0 * E_;

    int srowA = wv * 16 + (lane >> 2);
    int sc16  = lane & 3;

    auto stage = [&](int buf, int k0) {
        #pragma unroll
        for (int is = 0; is < 2; ++is) {
            int row = is * 64 + srowA;
            const char* src = (const char*)(Am + (size_t)row * E_ + k0) + ((sc16 ^ ((row >> 1) & 3)) << 4);
            gll16(src, &ldsA[buf][is * 2048 + wv * 512]);
        }
        {
            int row = srowA;
            const char* src = (const char*)(Bm + (size_t)row * E_ + k0) + ((sc16 ^ ((row >> 1) & 3)) << 4);
            gll16(src, &ldsB[buf][wv * 512]);
        }
    };

    f32x4 acc[4][2];
    #pragma unroll
    for (int mi = 0; mi < 4; ++mi)
        #pragma unroll
        for (int nj = 0; nj < 2; ++nj) acc[mi][nj] = (f32x4){0.f, 0.f, 0.f, 0.f};

    stage(0, 0);
    __syncthreads();
    for (int t = 0; t < E_ / 32; ++t) {
        if (t + 1 < E_ / 32) stage((t + 1) & 1, (t + 1) * 32);
        const _Float16* At = ldsA[t & 1];
        const _Float16* Bt = ldsB[t & 1];
        half8 af[4], bf[2];
        #pragma unroll
        for (int mi = 0; mi < 4; ++mi) {
            int row = wm * 64 + mi * 16 + l15;
            af[mi] = *reinterpret_cast<const half8*>(At + row * 32 + ((lhi ^ ((row >> 1) & 3)) << 3));
        }
        #pragma unroll
        for (int nj = 0; nj < 2; ++nj) {
            int row = wn * 32 + nj * 16 + l15;
            bf[nj] = *reinterpret_cast<const half8*>(Bt + row * 32 + ((lhi ^ ((row >> 1) & 3)) << 3));
        }
        #pragma unroll
        for (int mi = 0; mi < 4; ++mi)
            #pragma unroll
            for (int nj = 0; nj < 2; ++nj) acc[mi][nj] = mfma16(af[mi], bf[nj], acc[mi][nj]);
        __syncthreads();
    }

    #pragma unroll
    for (int nj = 0; nj < 2; ++nj) {
        int col = n0 + wn * 32 + nj * 16 + l15;
        float bsv = bo[col];
        #pragma unroll
        for (int mi = 0; mi < 4; ++mi) {
            #pragma unroll
            for (int r = 0; r < 4; ++r) {
                int token = m0 + wm * 64 + mi * 16 + lhi * 4 + r;
                out[(size_t)token * E_ + col] = acc[mi][nj][r] + bsv;
            }
        }
    }
}

extern "C" void kernel_launch(void* const* d_in, const int* in_sizes, int n_in,
                              void* d_out, int out_size, void* d_ws, size_t ws_size,
                              hipStream_t stream) {
    const float* x  = (const float*)d_in[0];
    const float* Wq = (const float*)d_in[1];
    const float* bq = (const float*)d_in[2];
    const float* Wk = (const float*)d_in[3];
    const float* bk = (const float*)d_in[4];
    const float* Wv = (const float*)d_in[5];
    const float* bv = (const float*)d_in[6];
    const float* Wo = (const float*)d_in[7];
    const float* bo = (const float*)d_in[8];

    char* ws = (char*)d_ws;
    _Float16* xh   = (_Float16*)(ws);                 // 4096*768           = 6,291,456 B
    _Float16* Wt   = (_Float16*)(ws + 6291456);       // 4*768*768          = 4,718,592 B
    _Float16* qw   = (_Float16*)(ws + 11010048);      // [B,H,S,D]          = 6,291,456 B
    _Float16* kw   = (_Float16*)(ws + 17301504);      // [B,H,S,D]          = 6,291,456 B
    _Float16* vT   = (_Float16*)(ws + 23592960);      // [B,H,D,S]          = 6,291,456 B
    _Float16* aout = (_Float16*)(ws + 29884416);      // [B*S,E]            = 6,291,456 B
    (void)ws_size; (void)in_sizes; (void)n_in; (void)out_size;

    float* out  = (float*)d_out;                       // (B,S,E) f32
    float* wout = out + (size_t)BS_ * E_;              // (B,H,S,S) f32

    cast_x_kernel<<<dim3(BS_ * E_ / 1024), dim3(256), 0, stream>>>(x, xh, BS_ * E_);
    transpose_w_kernel<<<dim3(E_ / 32, E_ / 32, 4), dim3(256), 0, stream>>>(Wq, Wk, Wv, Wo, Wt);
    qkv_kernel<<<dim3(3 * E_ / 64, BS_ / 128), dim3(256), 0, stream>>>(xh, Wt, bq, bk, bv, qw, kw, vT);
    attn_kernel<<<dim3(S_ / 64, H_, B_), dim3(256), 0, stream>>>(qw, kw, vT, wout, aout);
    proj_kernel<<<dim3(E_ / 64, BS_ / 128), dim3(256), 0, stream>>>(aout, Wt + (size_t)3 * E_ * E_, bo, out);
}